// Round 2
// baseline (751.849 us; speedup 1.0000x reference)
//
#include <hip/hip_runtime.h>
#include <stdint.h>
#include <stddef.h>

// ---------------------------------------------------------------------------
// Qwen2 decoder layer, MI355X (gfx950).
// B=2 S=2048 H=896 NH=7 NKV=1 D=128 I=4864.  M = B*S = 4096 rows.
// Round 2: dtype-self-detecting. Inputs may be fp32 or bf16 on device; a
// probe kernel detects which, inputs are normalized to bf16 ws copies, and
// the final GEMM writes d_out as fp32 or bf16 per the detected flag.
// ---------------------------------------------------------------------------

typedef unsigned short u16;
typedef __bf16 bf16x8 __attribute__((ext_vector_type(8)));
typedef u16    u16x8  __attribute__((ext_vector_type(8)));
typedef float  f32x4  __attribute__((ext_vector_type(4)));

__device__ inline float b2f(u16 u) {
  union { unsigned int i; float f; } v; v.i = ((unsigned int)u) << 16; return v.f;
}
__device__ inline u16 f2b(float f) {
  union { float f; unsigned int i; } v; v.f = f;
  unsigned int r = v.i + 0x7FFFu + ((v.i >> 16) & 1u);   // RNE
  return (u16)(r >> 16);
}

__device__ inline f32x4 mfma16(bf16x8 a, bf16x8 b, f32x4 c) {
  return __builtin_amdgcn_mfma_f32_16x16x32_bf16(a, b, c, 0, 0, 0);
}

// async global->LDS, 16B per lane. LDS dest is wave-uniform base (+lane*16 by HW).
__device__ inline void gload_lds16(const u16* g, u16* l) {
  __builtin_amdgcn_global_load_lds((__attribute__((address_space(1))) void*)g,
                                   (__attribute__((address_space(3))) void*)l,
                                   16, 0, 0);
}

template<int ITERS>
__device__ inline void stage_lds64(const u16* __restrict__ g, int ld, u16* lds, int t) {
  int wub = t & 192;                       // wave-uniform part of t
  #pragma unroll
  for (int i = 0; i < ITERS; ++i) {
    int e8 = i * 256 + t;
    int r = e8 >> 3, c = (e8 & 7) << 3;    // 8 chunks per 64-elem row
    gload_lds16(g + (size_t)r * ld + c, lds + (i * 256 + wub) * 8);
  }
}
__device__ inline void stage_lds128(const u16* __restrict__ g, int ld, u16* lds, int t) {
  int wub = t & 192;
  #pragma unroll
  for (int i = 0; i < 2; ++i) {
    int e8 = i * 256 + t;
    int r = e8 >> 4, c = (e8 & 15) << 3;   // 16 chunks per 128-elem row
    gload_lds16(g + (size_t)r * ld + c, lds + (i * 256 + wub) * 8);
  }
}

// ---------------------------------------------------------------------------
// Dtype probe: read 1024 u32 words of hidden_states; low u16 as bf16 must be
// sane (|v| in [1e-30,1e5] or 0) if the buffer is bf16 pairs. fp32 buffers
// put random mantissa bits there -> ~40% "weird". flag=1 => fp32 inputs.
// ---------------------------------------------------------------------------
__global__ __launch_bounds__(256) void detect_k(const unsigned int* __restrict__ x,
                                                int* __restrict__ flag) {
  __shared__ int red[4];
  int t = threadIdx.x;
  int weird = 0;
  #pragma unroll
  for (int i = 0; i < 4; ++i) {
    unsigned int w = x[t * 4 + i];
    float a = fabsf(b2f((u16)(w & 0xFFFF)));
    if (!(a <= 1e5f)) weird++;                       // catches >1e5 and NaN
    else if (a != 0.0f && a < 1e-30f) weird++;       // catches denormal junk
  }
  #pragma unroll
  for (int off = 32; off; off >>= 1) weird += __shfl_xor(weird, off);
  if ((t & 63) == 0) red[t >> 6] = weird;
  __syncthreads();
  if (t == 0) flag[0] = (red[0] + red[1] + red[2] + red[3] > 64) ? 1 : 0;
}

// ---------------------------------------------------------------------------
// Batched input normalization: 15 tensors -> bf16 copies in ws.
// ---------------------------------------------------------------------------
struct CvtJob { const void* src; u16* dst; int n; };
struct CvtJobs { CvtJob j[15]; };

__global__ __launch_bounds__(256) void convert_k(CvtJobs jobs, const int* __restrict__ flag) {
  CvtJob c = jobs.j[blockIdx.y];
  int idx = (blockIdx.x * 256 + threadIdx.x) * 8;
  if (idx >= c.n) return;
  if (*flag) {
    const float* s = (const float*)c.src;
    u16x8 o;
    #pragma unroll
    for (int i = 0; i < 8; ++i) o[i] = f2b(s[idx + i]);
    *(u16x8*)(c.dst + idx) = o;
  } else {
    *(u16x8*)(c.dst + idx) = *(const u16x8*)((const u16*)c.src + idx);
  }
}

// ---------------------------------------------------------------------------
// RMSNorm: rows of 896, block = 448 threads (7 waves), 2 elems/thread.
// ---------------------------------------------------------------------------
__global__ __launch_bounds__(448) void rmsnorm_k(const u16* __restrict__ x,
                                                 const u16* __restrict__ w,
                                                 u16* __restrict__ out) {
  __shared__ float red[7];
  int t = threadIdx.x;
  size_t row = blockIdx.x;
  const u16* xr = x + row * 896;
  unsigned int pair = *(const unsigned int*)&xr[t * 2];
  float v0 = b2f((u16)(pair & 0xFFFF)), v1 = b2f((u16)(pair >> 16));
  float ss = v0 * v0 + v1 * v1;
  #pragma unroll
  for (int off = 32; off; off >>= 1) ss += __shfl_xor(ss, off);
  if ((t & 63) == 0) red[t >> 6] = ss;
  __syncthreads();
  float tot = red[0] + red[1] + red[2] + red[3] + red[4] + red[5] + red[6];
  float inv = rsqrtf(tot * (1.0f / 896.0f) + 1e-6f);
  unsigned int wp = *(const unsigned int*)&w[t * 2];
  unsigned int o = (unsigned int)f2b(v0 * inv * b2f((u16)(wp & 0xFFFF)))
                 | ((unsigned int)f2b(v1 * inv * b2f((u16)(wp >> 16))) << 16);
  *(unsigned int*)&out[row * 896 + t * 2] = o;
}

// ---------------------------------------------------------------------------
// QKV GEMM: A(4096x896) @ [wq;wk;wv]^T + bias -> qkv(4096x1152).
// ---------------------------------------------------------------------------
__global__ __launch_bounds__(256) void gemm_qkv(const u16* __restrict__ A,
    const u16* __restrict__ wq, const u16* __restrict__ bq,
    const u16* __restrict__ wk, const u16* __restrict__ bk,
    const u16* __restrict__ wv, const u16* __restrict__ bv,
    u16* __restrict__ C) {
  __shared__ u16 As[128 * 64], Bs[128 * 64];
  int t = threadIdx.x, lane = t & 63, w = t >> 6;
  int wm = w >> 1, wn = w & 1, lrow = lane & 15, lg = lane >> 4;
  int bx = blockIdx.x, row0 = blockIdx.y * 128;
  const u16 *W, *bias; int ocol;
  if (bx < 7)       { W = wq + (size_t)bx * 128 * 896; bias = bq + bx * 128; ocol = bx * 128; }
  else if (bx == 7) { W = wk; bias = bk; ocol = 896; }
  else              { W = wv; bias = bv; ocol = 1024; }

  f32x4 acc[4][4] = {};
  for (int kt = 0; kt < 896; kt += 64) {
    stage_lds64<4>(A + (size_t)row0 * 896 + kt, 896, As, t);
    stage_lds64<4>(W + kt, 896, Bs, t);
    __syncthreads();
    #pragma unroll
    for (int kk = 0; kk < 2; ++kk) {
      bf16x8 af[4], bf[4];
      #pragma unroll
      for (int m = 0; m < 4; ++m)
        af[m] = *(const bf16x8*)&As[(wm * 64 + m * 16 + lrow) * 64 + kk * 32 + lg * 8];
      #pragma unroll
      for (int n = 0; n < 4; ++n)
        bf[n] = *(const bf16x8*)&Bs[(wn * 64 + n * 16 + lrow) * 64 + kk * 32 + lg * 8];
      #pragma unroll
      for (int m = 0; m < 4; ++m)
        #pragma unroll
        for (int n = 0; n < 4; ++n)
          acc[m][n] = mfma16(af[m], bf[n], acc[m][n]);
    }
    __syncthreads();
  }
  #pragma unroll
  for (int m = 0; m < 4; ++m)
    #pragma unroll
    for (int n = 0; n < 4; ++n) {
      int col = wn * 64 + n * 16 + lrow;
      float bb = b2f(bias[col]);
      #pragma unroll
      for (int j = 0; j < 4; ++j) {
        size_t row = row0 + wm * 64 + m * 16 + lg * 4 + j;
        C[row * 1152 + ocol + col] = f2b(acc[m][n][j] + bb);
      }
    }
}

// ---------------------------------------------------------------------------
// Generic C = A @ W^T (+ residual). BM=BN=128, BK=64.
// DYNOUT: branch output dtype on *flag (1=fp32, 0=bf16). Else bf16 out.
// ---------------------------------------------------------------------------
template<bool RES, bool DYNOUT>
__global__ __launch_bounds__(256) void gemm_bt(const u16* __restrict__ A,
    const u16* __restrict__ W, const u16* __restrict__ resid,
    void* __restrict__ Cp, const int* __restrict__ flag, int K, int ldc) {
  __shared__ u16 As[128 * 64], Bs[128 * 64];
  int t = threadIdx.x, lane = t & 63, w = t >> 6;
  int wm = w >> 1, wn = w & 1, lrow = lane & 15, lg = lane >> 4;
  int col0 = blockIdx.x * 128, row0 = blockIdx.y * 128;
  int f32out = DYNOUT ? *flag : 0;

  f32x4 acc[4][4] = {};
  for (int kt = 0; kt < K; kt += 64) {
    stage_lds64<4>(A + (size_t)row0 * K + kt, K, As, t);
    stage_lds64<4>(W + (size_t)col0 * K + kt, K, Bs, t);
    __syncthreads();
    #pragma unroll
    for (int kk = 0; kk < 2; ++kk) {
      bf16x8 af[4], bf[4];
      #pragma unroll
      for (int m = 0; m < 4; ++m)
        af[m] = *(const bf16x8*)&As[(wm * 64 + m * 16 + lrow) * 64 + kk * 32 + lg * 8];
      #pragma unroll
      for (int n = 0; n < 4; ++n)
        bf[n] = *(const bf16x8*)&Bs[(wn * 64 + n * 16 + lrow) * 64 + kk * 32 + lg * 8];
      #pragma unroll
      for (int m = 0; m < 4; ++m)
        #pragma unroll
        for (int n = 0; n < 4; ++n)
          acc[m][n] = mfma16(af[m], bf[n], acc[m][n]);
    }
    __syncthreads();
  }
  #pragma unroll
  for (int m = 0; m < 4; ++m)
    #pragma unroll
    for (int n = 0; n < 4; ++n) {
      int col = col0 + wn * 64 + n * 16 + lrow;
      #pragma unroll
      for (int j = 0; j < 4; ++j) {
        size_t row = row0 + wm * 64 + m * 16 + lg * 4 + j;
        float v = acc[m][n][j];
        if (RES) v += b2f(resid[row * (size_t)ldc + col]);
        if (DYNOUT && f32out) ((float*)Cp)[row * (size_t)ldc + col] = v;
        else                  ((u16*)Cp)[row * (size_t)ldc + col] = f2b(v);
      }
    }
}

// ---------------------------------------------------------------------------
// Fused gate/up GEMM + SiLU*up.  BM=128, BN=64, dual accumulators.
// ---------------------------------------------------------------------------
__global__ __launch_bounds__(256) void gemm_gateup(const u16* __restrict__ A,
    const u16* __restrict__ Wg, const u16* __restrict__ Wu,
    u16* __restrict__ act) {
  __shared__ u16 As[128 * 64], Bg[64 * 64], Bu[64 * 64];
  int t = threadIdx.x, lane = t & 63, w = t >> 6;
  int wm = w >> 1, wn = w & 1, lrow = lane & 15, lg = lane >> 4;
  int col0 = blockIdx.x * 64, row0 = blockIdx.y * 128;

  f32x4 ag[4][2] = {}, au[4][2] = {};
  for (int kt = 0; kt < 896; kt += 64) {
    stage_lds64<4>(A + (size_t)row0 * 896 + kt, 896, As, t);
    stage_lds64<2>(Wg + (size_t)col0 * 896 + kt, 896, Bg, t);
    stage_lds64<2>(Wu + (size_t)col0 * 896 + kt, 896, Bu, t);
    __syncthreads();
    #pragma unroll
    for (int kk = 0; kk < 2; ++kk) {
      bf16x8 af[4], bg[2], bu[2];
      #pragma unroll
      for (int m = 0; m < 4; ++m)
        af[m] = *(const bf16x8*)&As[(wm * 64 + m * 16 + lrow) * 64 + kk * 32 + lg * 8];
      #pragma unroll
      for (int n = 0; n < 2; ++n) {
        bg[n] = *(const bf16x8*)&Bg[(wn * 32 + n * 16 + lrow) * 64 + kk * 32 + lg * 8];
        bu[n] = *(const bf16x8*)&Bu[(wn * 32 + n * 16 + lrow) * 64 + kk * 32 + lg * 8];
      }
      #pragma unroll
      for (int m = 0; m < 4; ++m)
        #pragma unroll
        for (int n = 0; n < 2; ++n) {
          ag[m][n] = mfma16(af[m], bg[n], ag[m][n]);
          au[m][n] = mfma16(af[m], bu[n], au[m][n]);
        }
    }
    __syncthreads();
  }
  #pragma unroll
  for (int m = 0; m < 4; ++m)
    #pragma unroll
    for (int n = 0; n < 2; ++n) {
      int col = col0 + wn * 32 + n * 16 + lrow;
      #pragma unroll
      for (int j = 0; j < 4; ++j) {
        size_t row = row0 + wm * 64 + m * 16 + lg * 4 + j;
        float g = ag[m][n][j], u = au[m][n][j];
        float silu = g / (1.0f + __expf(-g));
        act[row * 4864 + col] = f2b(silu * u);
      }
    }
}

// ---------------------------------------------------------------------------
// RoPE in-place on q (7 heads) and k (1 head) inside qkv(4096 x 1152).
// ---------------------------------------------------------------------------
__global__ __launch_bounds__(64) void rope_k(u16* __restrict__ qkv,
                                             const u16* __restrict__ cosb,
                                             const u16* __restrict__ sinb) {
  int d = threadIdx.x;              // 0..63
  int hidx = blockIdx.x;            // 0..7 (7 = the single k head)
  size_t row = blockIdx.y;          // 0..4095
  int s = (int)(row & 2047);
  int cb = hidx < 7 ? hidx * 128 : 896;
  u16* p = qkv + row * 1152 + cb;
  float x1 = b2f(p[d]), x2 = b2f(p[d + 64]);
  float c = b2f(cosb[s * 128 + d]), sn = b2f(sinb[s * 128 + d]);
  p[d]      = f2b(x1 * c - x2 * sn);
  p[d + 64] = f2b(x1 * sn + x2 * c);
}

// ---------------------------------------------------------------------------
// Flash attention, causal, GQA (kv head 0 for all 7 q heads).
// Grid (32 q-blocks, 14 bh). 256 thr = 4 waves, 16 q-rows per wave, KBLK=32.
// ---------------------------------------------------------------------------
__global__ __launch_bounds__(256) void attn_k(const u16* __restrict__ qkv,
                                              u16* __restrict__ out) {
  __shared__ u16 Ks[32 * 128];        // K tile, row-major
  __shared__ u16 Vt[128 * 40];        // V tile transposed [d][k], pad to 40
  __shared__ u16 Ps[4][16 * 40];      // per-wave P tile [q][k], pad to 40
  int t = threadIdx.x, lane = t & 63, w = t >> 6;
  int lrow = lane & 15, lg = lane >> 4;
  int qb = blockIdx.x, bh = blockIdx.y;
  int b = bh / 7, h = bh % 7;
  int q0 = qb * 64 + w * 16;

  const u16* qbase = qkv + ((size_t)b * 2048 + q0) * 1152 + h * 128;
  bf16x8 qf[4];
  #pragma unroll
  for (int kk = 0; kk < 4; ++kk)
    qf[kk] = *(const bf16x8*)(qbase + (size_t)lrow * 1152 + kk * 32 + lg * 8);

  f32x4 oa[8] = {};
  float m_run[4], l_run[4];
  #pragma unroll
  for (int j = 0; j < 4; ++j) { m_run[j] = -1e30f; l_run[j] = 0.0f; }

  const u16* kbase = qkv + (size_t)b * 2048 * 1152 + 896;
  const u16* vbase = qkv + (size_t)b * 2048 * 1152 + 1024;
  int ntiles = 2 * qb + 2;

  for (int kt = 0; kt < ntiles; ++kt) {
    int k0 = kt * 32;
    stage_lds128(kbase + (size_t)k0 * 1152, 1152, Ks, t);
    #pragma unroll
    for (int i = 0; i < 2; ++i) {           // V transpose staging
      int e8 = i * 256 + t;
      int r = e8 >> 4, c = (e8 & 15) << 3;
      u16x8 v8 = *(const u16x8*)(vbase + (size_t)(k0 + r) * 1152 + c);
      #pragma unroll
      for (int j = 0; j < 8; ++j) Vt[(c + j) * 40 + r] = v8[j];
    }
    __syncthreads();

    if (k0 <= q0 + 15) {
      f32x4 sa[2] = {};
      #pragma unroll
      for (int kk = 0; kk < 4; ++kk)
        #pragma unroll
        for (int nf = 0; nf < 2; ++nf) {
          bf16x8 kf = *(const bf16x8*)&Ks[(nf * 16 + lrow) * 128 + kk * 32 + lg * 8];
          sa[nf] = mfma16(qf[kk], kf, sa[nf]);
        }
      float s[2][4], mx[4];
      #pragma unroll
      for (int j = 0; j < 4; ++j) {
        int qrow = q0 + lg * 4 + j;
        #pragma unroll
        for (int nf = 0; nf < 2; ++nf) {
          int kc = k0 + nf * 16 + lrow;
          float v = sa[nf][j] * 0.08838834764831845f;
          s[nf][j] = (kc > qrow) ? -1e30f : v;
        }
        mx[j] = fmaxf(s[0][j], s[1][j]);
      }
      #pragma unroll
      for (int off = 1; off < 16; off <<= 1)
        #pragma unroll
        for (int j = 0; j < 4; ++j)
          mx[j] = fmaxf(mx[j], __shfl_xor(mx[j], off));
      float p[2][4], ps[4];
      #pragma unroll
      for (int j = 0; j < 4; ++j) {
        float mn = fmaxf(m_run[j], mx[j]);
        float al = __expf(m_run[j] - mn);
        m_run[j] = mn;
        p[0][j] = __expf(s[0][j] - mn);
        p[1][j] = __expf(s[1][j] - mn);
        ps[j] = p[0][j] + p[1][j];
        l_run[j] *= al;
        #pragma unroll
        for (int nf2 = 0; nf2 < 8; ++nf2) oa[nf2][j] *= al;
      }
      #pragma unroll
      for (int off = 1; off < 16; off <<= 1)
        #pragma unroll
        for (int j = 0; j < 4; ++j) ps[j] += __shfl_xor(ps[j], off);
      #pragma unroll
      for (int j = 0; j < 4; ++j) l_run[j] += ps[j];
      #pragma unroll
      for (int nf = 0; nf < 2; ++nf)
        #pragma unroll
        for (int j = 0; j < 4; ++j)
          Ps[w][(lg * 4 + j) * 40 + nf * 16 + lrow] = f2b(p[nf][j]);
      bf16x8 pf = *(const bf16x8*)&Ps[w][lrow * 40 + lg * 8];
      #pragma unroll
      for (int nf2 = 0; nf2 < 8; ++nf2) {
        bf16x8 vf = *(const bf16x8*)&Vt[(nf2 * 16 + lrow) * 40 + lg * 8];
        oa[nf2] = mfma16(pf, vf, oa[nf2]);
      }
    }
    __syncthreads();
  }

  u16* obase = out + ((size_t)b * 2048 + q0) * 896 + h * 128;
  #pragma unroll
  for (int j = 0; j < 4; ++j) {
    float rl = 1.0f / l_run[j];
    #pragma unroll
    for (int nf2 = 0; nf2 < 8; ++nf2)
      obase[(size_t)(lg * 4 + j) * 896 + nf2 * 16 + lrow] = f2b(oa[nf2][j] * rl);
  }
}

// ---------------------------------------------------------------------------
extern "C" void kernel_launch(void* const* d_in, const int* in_sizes, int n_in,
                              void* d_out, int out_size, void* d_ws, size_t ws_size,
                              hipStream_t stream) {
  // sizes
  const int nX = 4096 * 896, nWQ = 896 * 896, nBQ = 896, nWK = 128 * 896, nBK = 128;
  const int nWV = 128 * 896, nBV = 128, nWO = 896 * 896;
  const int nWG = 4864 * 896, nWU = 4864 * 896, nWD = 896 * 4864;
  const int nLN = 896, nCS = 2048 * 128;

  u16* ws = (u16*)d_ws;
  int* flag = (int*)ws;
  size_t off = 16;
  auto alloc = [&](size_t n) { u16* p = ws + off; off += n; return p; };
  u16* cx   = alloc(nX);
  u16* cwq  = alloc(nWQ);  u16* cbq = alloc(nBQ);
  u16* cwk  = alloc(nWK);  u16* cbk = alloc(nBK);
  u16* cwv  = alloc(nWV);  u16* cbv = alloc(nBV);
  u16* cwo  = alloc(nWO);
  u16* cwg  = alloc(nWG);  u16* cwu = alloc(nWU);  u16* cwd = alloc(nWD);
  u16* cln1 = alloc(nLN);  u16* cln2 = alloc(nLN);
  u16* ccos = alloc(nCS);  u16* csin = alloc(nCS);
  u16* h    = alloc(4096 * 896);
  u16* qkv  = alloc(4096 * 1152);
  u16* attn = alloc(4096 * 896);
  u16* x2   = alloc(4096 * 896);
  u16* act  = alloc((size_t)4096 * 4864);

  detect_k<<<1, 256, 0, stream>>>((const unsigned int*)d_in[0], flag);

  CvtJobs jobs;
  const void* srcs[15] = { d_in[0], d_in[1], d_in[2], d_in[3], d_in[4], d_in[5],
                           d_in[6], d_in[7], d_in[8], d_in[9], d_in[10],
                           d_in[11], d_in[12], d_in[14], d_in[15] };
  u16* dsts[15] = { cx, cwq, cbq, cwk, cbk, cwv, cbv, cwo, cwg, cwu, cwd,
                    cln1, cln2, ccos, csin };
  int  ns[15]   = { nX, nWQ, nBQ, nWK, nBK, nWV, nBV, nWO, nWG, nWU, nWD,
                    nLN, nLN, nCS, nCS };
  for (int i = 0; i < 15; ++i) { jobs.j[i].src = srcs[i]; jobs.j[i].dst = dsts[i]; jobs.j[i].n = ns[i]; }
  convert_k<<<dim3(2128, 15), 256, 0, stream>>>(jobs, flag);

  rmsnorm_k <<<4096, 448, 0, stream>>>(cx, cln1, h);
  gemm_qkv  <<<dim3(9, 32),  256, 0, stream>>>(h, cwq, cbq, cwk, cbk, cwv, cbv, qkv);
  rope_k    <<<dim3(8, 4096), 64, 0, stream>>>(qkv, ccos, csin);
  attn_k    <<<dim3(32, 14), 256, 0, stream>>>(qkv, attn);
  gemm_bt<true, false> <<<dim3(7, 32), 256, 0, stream>>>(attn, cwo, cx, (void*)x2, flag, 896, 896);
  rmsnorm_k <<<4096, 448, 0, stream>>>(x2, cln2, h);
  gemm_gateup <<<dim3(76, 32), 256, 0, stream>>>(h, cwg, cwu, act);
  gemm_bt<true, true> <<<dim3(7, 32), 256, 0, stream>>>(act, cwd, x2, d_out, flag, 4864, 896);
}

// Round 3
// 581.804 us; speedup vs baseline: 1.2923x; 1.2923x over previous
//
#include <hip/hip_runtime.h>
#include <stdint.h>
#include <stddef.h>

// ---------------------------------------------------------------------------
// Qwen2 decoder layer, MI355X (gfx950).
// B=2 S=2048 H=896 NH=7 NKV=1 D=128 I=4864.  M = B*S = 4096 rows.
// Inputs detected fp32 (round-2); converted to bf16 ws copies; out fp32.
// Round 3: attention rewritten — paired causal q-tiles, KVBLK=64, XOR-swizzled
// LDS (K via pre-swizzled gload_lds source), conflict-free V transpose,
// 2-phase prefetch. RoPE re-blocked to 256 threads.
// ---------------------------------------------------------------------------

typedef unsigned short u16;
typedef unsigned long long u64;
typedef __bf16 bf16x8 __attribute__((ext_vector_type(8)));
typedef u16    u16x8  __attribute__((ext_vector_type(8)));
typedef float  f32x4  __attribute__((ext_vector_type(4)));

__device__ inline float b2f(u16 u) {
  union { unsigned int i; float f; } v; v.i = ((unsigned int)u) << 16; return v.f;
}
__device__ inline u16 f2b(float f) {
  union { float f; unsigned int i; } v; v.f = f;
  unsigned int r = v.i + 0x7FFFu + ((v.i >> 16) & 1u);   // RNE
  return (u16)(r >> 16);
}

__device__ inline f32x4 mfma16(bf16x8 a, bf16x8 b, f32x4 c) {
  return __builtin_amdgcn_mfma_f32_16x16x32_bf16(a, b, c, 0, 0, 0);
}

// async global->LDS, 16B per lane. LDS dest is wave-uniform base (+lane*16 by HW).
__device__ inline void gload_lds16(const u16* g, u16* l) {
  __builtin_amdgcn_global_load_lds((__attribute__((address_space(1))) void*)g,
                                   (__attribute__((address_space(3))) void*)l,
                                   16, 0, 0);
}

template<int ITERS>
__device__ inline void stage_lds64(const u16* __restrict__ g, int ld, u16* lds, int t) {
  int wub = t & 192;                       // wave-uniform part of t
  #pragma unroll
  for (int i = 0; i < ITERS; ++i) {
    int e8 = i * 256 + t;
    int r = e8 >> 3, c = (e8 & 7) << 3;    // 8 chunks per 64-elem row
    gload_lds16(g + (size_t)r * ld + c, lds + (i * 256 + wub) * 8);
  }
}

// ---------------------------------------------------------------------------
// Dtype probe (fp32 vs bf16 input buffers).
// ---------------------------------------------------------------------------
__global__ __launch_bounds__(256) void detect_k(const unsigned int* __restrict__ x,
                                                int* __restrict__ flag) {
  __shared__ int red[4];
  int t = threadIdx.x;
  int weird = 0;
  #pragma unroll
  for (int i = 0; i < 4; ++i) {
    unsigned int w = x[t * 4 + i];
    float a = fabsf(b2f((u16)(w & 0xFFFF)));
    if (!(a <= 1e5f)) weird++;
    else if (a != 0.0f && a < 1e-30f) weird++;
  }
  #pragma unroll
  for (int off = 32; off; off >>= 1) weird += __shfl_xor(weird, off);
  if ((t & 63) == 0) red[t >> 6] = weird;
  __syncthreads();
  if (t == 0) flag[0] = (red[0] + red[1] + red[2] + red[3] > 64) ? 1 : 0;
}

// ---------------------------------------------------------------------------
// Batched input normalization: 15 tensors -> bf16 copies in ws.
// ---------------------------------------------------------------------------
struct CvtJob { const void* src; u16* dst; int n; };
struct CvtJobs { CvtJob j[15]; };

__global__ __launch_bounds__(256) void convert_k(CvtJobs jobs, const int* __restrict__ flag) {
  CvtJob c = jobs.j[blockIdx.y];
  int idx = (blockIdx.x * 256 + threadIdx.x) * 8;
  if (idx >= c.n) return;
  if (*flag) {
    const float* s = (const float*)c.src;
    u16x8 o;
    #pragma unroll
    for (int i = 0; i < 8; ++i) o[i] = f2b(s[idx + i]);
    *(u16x8*)(c.dst + idx) = o;
  } else {
    *(u16x8*)(c.dst + idx) = *(const u16x8*)((const u16*)c.src + idx);
  }
}

// ---------------------------------------------------------------------------
// RMSNorm: rows of 896, block = 448 threads (7 waves), 2 elems/thread.
// ---------------------------------------------------------------------------
__global__ __launch_bounds__(448) void rmsnorm_k(const u16* __restrict__ x,
                                                 const u16* __restrict__ w,
                                                 u16* __restrict__ out) {
  __shared__ float red[7];
  int t = threadIdx.x;
  size_t row = blockIdx.x;
  const u16* xr = x + row * 896;
  unsigned int pair = *(const unsigned int*)&xr[t * 2];
  float v0 = b2f((u16)(pair & 0xFFFF)), v1 = b2f((u16)(pair >> 16));
  float ss = v0 * v0 + v1 * v1;
  #pragma unroll
  for (int off = 32; off; off >>= 1) ss += __shfl_xor(ss, off);
  if ((t & 63) == 0) red[t >> 6] = ss;
  __syncthreads();
  float tot = red[0] + red[1] + red[2] + red[3] + red[4] + red[5] + red[6];
  float inv = rsqrtf(tot * (1.0f / 896.0f) + 1e-6f);
  unsigned int wp = *(const unsigned int*)&w[t * 2];
  unsigned int o = (unsigned int)f2b(v0 * inv * b2f((u16)(wp & 0xFFFF)))
                 | ((unsigned int)f2b(v1 * inv * b2f((u16)(wp >> 16))) << 16);
  *(unsigned int*)&out[row * 896 + t * 2] = o;
}

// ---------------------------------------------------------------------------
// QKV GEMM: A(4096x896) @ [wq;wk;wv]^T + bias -> qkv(4096x1152).
// ---------------------------------------------------------------------------
__global__ __launch_bounds__(256) void gemm_qkv(const u16* __restrict__ A,
    const u16* __restrict__ wq, const u16* __restrict__ bq,
    const u16* __restrict__ wk, const u16* __restrict__ bk,
    const u16* __restrict__ wv, const u16* __restrict__ bv,
    u16* __restrict__ C) {
  __shared__ u16 As[128 * 64], Bs[128 * 64];
  int t = threadIdx.x, lane = t & 63, w = t >> 6;
  int wm = w >> 1, wn = w & 1, lrow = lane & 15, lg = lane >> 4;
  int bx = blockIdx.x, row0 = blockIdx.y * 128;
  const u16 *W, *bias; int ocol;
  if (bx < 7)       { W = wq + (size_t)bx * 128 * 896; bias = bq + bx * 128; ocol = bx * 128; }
  else if (bx == 7) { W = wk; bias = bk; ocol = 896; }
  else              { W = wv; bias = bv; ocol = 1024; }

  f32x4 acc[4][4] = {};
  for (int kt = 0; kt < 896; kt += 64) {
    stage_lds64<4>(A + (size_t)row0 * 896 + kt, 896, As, t);
    stage_lds64<4>(W + kt, 896, Bs, t);
    __syncthreads();
    #pragma unroll
    for (int kk = 0; kk < 2; ++kk) {
      bf16x8 af[4], bf[4];
      #pragma unroll
      for (int m = 0; m < 4; ++m)
        af[m] = *(const bf16x8*)&As[(wm * 64 + m * 16 + lrow) * 64 + kk * 32 + lg * 8];
      #pragma unroll
      for (int n = 0; n < 4; ++n)
        bf[n] = *(const bf16x8*)&Bs[(wn * 64 + n * 16 + lrow) * 64 + kk * 32 + lg * 8];
      #pragma unroll
      for (int m = 0; m < 4; ++m)
        #pragma unroll
        for (int n = 0; n < 4; ++n)
          acc[m][n] = mfma16(af[m], bf[n], acc[m][n]);
    }
    __syncthreads();
  }
  #pragma unroll
  for (int m = 0; m < 4; ++m)
    #pragma unroll
    for (int n = 0; n < 4; ++n) {
      int col = wn * 64 + n * 16 + lrow;
      float bb = b2f(bias[col]);
      #pragma unroll
      for (int j = 0; j < 4; ++j) {
        size_t row = row0 + wm * 64 + m * 16 + lg * 4 + j;
        C[row * 1152 + ocol + col] = f2b(acc[m][n][j] + bb);
      }
    }
}

// ---------------------------------------------------------------------------
// Generic C = A @ W^T (+ residual). BM=BN=128, BK=64.
// DYNOUT: branch output dtype on *flag (1=fp32, 0=bf16).
// ---------------------------------------------------------------------------
template<bool RES, bool DYNOUT>
__global__ __launch_bounds__(256) void gemm_bt(const u16* __restrict__ A,
    const u16* __restrict__ W, const u16* __restrict__ resid,
    void* __restrict__ Cp, const int* __restrict__ flag, int K, int ldc) {
  __shared__ u16 As[128 * 64], Bs[128 * 64];
  int t = threadIdx.x, lane = t & 63, w = t >> 6;
  int wm = w >> 1, wn = w & 1, lrow = lane & 15, lg = lane >> 4;
  int col0 = blockIdx.x * 128, row0 = blockIdx.y * 128;
  int f32out = DYNOUT ? *flag : 0;

  f32x4 acc[4][4] = {};
  for (int kt = 0; kt < K; kt += 64) {
    stage_lds64<4>(A + (size_t)row0 * K + kt, K, As, t);
    stage_lds64<4>(W + (size_t)col0 * K + kt, K, Bs, t);
    __syncthreads();
    #pragma unroll
    for (int kk = 0; kk < 2; ++kk) {
      bf16x8 af[4], bf[4];
      #pragma unroll
      for (int m = 0; m < 4; ++m)
        af[m] = *(const bf16x8*)&As[(wm * 64 + m * 16 + lrow) * 64 + kk * 32 + lg * 8];
      #pragma unroll
      for (int n = 0; n < 4; ++n)
        bf[n] = *(const bf16x8*)&Bs[(wn * 64 + n * 16 + lrow) * 64 + kk * 32 + lg * 8];
      #pragma unroll
      for (int m = 0; m < 4; ++m)
        #pragma unroll
        for (int n = 0; n < 4; ++n)
          acc[m][n] = mfma16(af[m], bf[n], acc[m][n]);
    }
    __syncthreads();
  }
  #pragma unroll
  for (int m = 0; m < 4; ++m)
    #pragma unroll
    for (int n = 0; n < 4; ++n) {
      int col = col0 + wn * 64 + n * 16 + lrow;
      #pragma unroll
      for (int j = 0; j < 4; ++j) {
        size_t row = row0 + wm * 64 + m * 16 + lg * 4 + j;
        float v = acc[m][n][j];
        if (RES) v += b2f(resid[row * (size_t)ldc + col]);
        if (DYNOUT && f32out) ((float*)Cp)[row * (size_t)ldc + col] = v;
        else                  ((u16*)Cp)[row * (size_t)ldc + col] = f2b(v);
      }
    }
}

// ---------------------------------------------------------------------------
// Fused gate/up GEMM + SiLU*up.  BM=128, BN=64, dual accumulators.
// ---------------------------------------------------------------------------
__global__ __launch_bounds__(256) void gemm_gateup(const u16* __restrict__ A,
    const u16* __restrict__ Wg, const u16* __restrict__ Wu,
    u16* __restrict__ act) {
  __shared__ u16 As[128 * 64], Bg[64 * 64], Bu[64 * 64];
  int t = threadIdx.x, lane = t & 63, w = t >> 6;
  int wm = w >> 1, wn = w & 1, lrow = lane & 15, lg = lane >> 4;
  int col0 = blockIdx.x * 64, row0 = blockIdx.y * 128;

  f32x4 ag[4][2] = {}, au[4][2] = {};
  for (int kt = 0; kt < 896; kt += 64) {
    stage_lds64<4>(A + (size_t)row0 * 896 + kt, 896, As, t);
    stage_lds64<2>(Wg + (size_t)col0 * 896 + kt, 896, Bg, t);
    stage_lds64<2>(Wu + (size_t)col0 * 896 + kt, 896, Bu, t);
    __syncthreads();
    #pragma unroll
    for (int kk = 0; kk < 2; ++kk) {
      bf16x8 af[4], bg[2], bu[2];
      #pragma unroll
      for (int m = 0; m < 4; ++m)
        af[m] = *(const bf16x8*)&As[(wm * 64 + m * 16 + lrow) * 64 + kk * 32 + lg * 8];
      #pragma unroll
      for (int n = 0; n < 2; ++n) {
        bg[n] = *(const bf16x8*)&Bg[(wn * 32 + n * 16 + lrow) * 64 + kk * 32 + lg * 8];
        bu[n] = *(const bf16x8*)&Bu[(wn * 32 + n * 16 + lrow) * 64 + kk * 32 + lg * 8];
      }
      #pragma unroll
      for (int m = 0; m < 4; ++m)
        #pragma unroll
        for (int n = 0; n < 2; ++n) {
          ag[m][n] = mfma16(af[m], bg[n], ag[m][n]);
          au[m][n] = mfma16(af[m], bu[n], au[m][n]);
        }
    }
    __syncthreads();
  }
  #pragma unroll
  for (int m = 0; m < 4; ++m)
    #pragma unroll
    for (int n = 0; n < 2; ++n) {
      int col = col0 + wn * 32 + n * 16 + lrow;
      #pragma unroll
      for (int j = 0; j < 4; ++j) {
        size_t row = row0 + wm * 64 + m * 16 + lg * 4 + j;
        float g = ag[m][n][j], u = au[m][n][j];
        float silu = g / (1.0f + __expf(-g));
        act[row * 4864 + col] = f2b(silu * u);
      }
    }
}

// ---------------------------------------------------------------------------
// RoPE in-place on q (7 heads) and k (1 head) inside qkv(4096 x 1152).
// 256-thr blocks: 4 (head) units per block.
// ---------------------------------------------------------------------------
__global__ __launch_bounds__(256) void rope_k(u16* __restrict__ qkv,
                                              const u16* __restrict__ cosb,
                                              const u16* __restrict__ sinb) {
  int t = threadIdx.x;
  int d = t & 63, hsub = t >> 6;
  int hidx = blockIdx.x * 4 + hsub;     // 0..7 (7 = the single k head)
  size_t row = blockIdx.y;              // 0..4095
  int s = (int)(row & 2047);
  int cb = hidx < 7 ? hidx * 128 : 896;
  u16* p = qkv + row * 1152 + cb;
  float x1 = b2f(p[d]), x2 = b2f(p[d + 64]);
  float c = b2f(cosb[s * 128 + d]), sn = b2f(sinb[s * 128 + d]);
  p[d]      = f2b(x1 * c - x2 * sn);
  p[d + 64] = f2b(x1 * sn + x2 * c);
}

// ---------------------------------------------------------------------------
// Flash attention v2: paired causal q-tiles, KVBLK=64, swizzled LDS.
// Grid (16 pairs, 14 bh), 256 thr = 4 waves, 16 q-rows per wave per tile.
// Swizzle: lds_byte(row,colbyte) = (row*stride + colbyte) ^ ((row&7)<<4).
// ---------------------------------------------------------------------------
__device__ inline void stageK_sw(u16* dst, const u16* kb, int k0, int t) {
  #pragma unroll
  for (int i = 0; i < 4; ++i) {
    int c = i * 256 + t;
    int row = c >> 4;
    int colb = ((c & 15) << 4) ^ ((row & 7) << 4);   // pre-swizzled source col
    gload_lds16(kb + (size_t)(k0 + row) * 1152 + (colb >> 1),
                dst + (i * 256 + (t & 192)) * 8);
  }
}
__device__ inline void loadV(u16x8* vr, const u16* vb, int k0, int t) {
  int kq = (t & 15) * 4, d0 = (t >> 4) * 8;
  #pragma unroll
  for (int i = 0; i < 4; ++i)
    vr[i] = *(const u16x8*)(vb + (size_t)(k0 + kq + i) * 1152 + d0);
}
__device__ inline void writeVt(u16* VtB, const u16x8* vr, int t) {
  int kq = (t & 15) * 4, d0 = (t >> 4) * 8;
  #pragma unroll
  for (int dj = 0; dj < 8; ++dj) {
    int d = d0 + dj;
    u64 val = (u64)vr[0][dj] | ((u64)vr[1][dj] << 16)
            | ((u64)vr[2][dj] << 32) | ((u64)vr[3][dj] << 48);
    *(u64*)((char*)VtB + ((d * 128 + kq * 2) ^ ((d & 7) << 4))) = val;
  }
}
__device__ inline bf16x8 ldSw(const u16* buf, int row, int stride, int colbyte) {
  int byte = (row * stride + colbyte) ^ ((row & 7) << 4);
  return *(const bf16x8*)((const char*)buf + byte);
}

__device__ inline void smax_tile(f32x4* sa, int q0, int k0, bool diag,
                                 float* m_run, float* l_run, f32x4* oa,
                                 u16* PsW, int lrow, int lg) {
  const float SC = 0.12753102f;   // D^-0.5 * log2(e)
  float s[4][4], mx[4];
  #pragma unroll
  for (int j = 0; j < 4; ++j) {
    int qrow = q0 + lg * 4 + j;
    #pragma unroll
    for (int nf = 0; nf < 4; ++nf) {
      float v = sa[nf][j] * SC;
      if (diag && (k0 + nf * 16 + lrow > qrow)) v = -1e30f;
      s[nf][j] = v;
    }
    mx[j] = fmaxf(fmaxf(s[0][j], s[1][j]), fmaxf(s[2][j], s[3][j]));
  }
  #pragma unroll
  for (int off = 1; off < 16; off <<= 1)
    #pragma unroll
    for (int j = 0; j < 4; ++j) mx[j] = fmaxf(mx[j], __shfl_xor(mx[j], off));
  float ps[4];
  #pragma unroll
  for (int j = 0; j < 4; ++j) {
    float mn = fmaxf(m_run[j], mx[j]);
    float al = exp2f(m_run[j] - mn);
    m_run[j] = mn;
    float sum = 0.0f;
    #pragma unroll
    for (int nf = 0; nf < 4; ++nf) {
      float pv = exp2f(s[nf][j] - mn);
      s[nf][j] = pv; sum += pv;
    }
    ps[j] = sum;
    l_run[j] *= al;
    #pragma unroll
    for (int nf2 = 0; nf2 < 8; ++nf2) oa[nf2][j] *= al;
  }
  #pragma unroll
  for (int off = 1; off < 16; off <<= 1)
    #pragma unroll
    for (int j = 0; j < 4; ++j) ps[j] += __shfl_xor(ps[j], off);
  #pragma unroll
  for (int j = 0; j < 4; ++j) l_run[j] += ps[j];
  // write P (swizzled)
  #pragma unroll
  for (int j = 0; j < 4; ++j) {
    int row = lg * 4 + j;
    #pragma unroll
    for (int nf = 0; nf < 4; ++nf) {
      int byte = (row * 128 + (nf * 16 + lrow) * 2) ^ ((row & 7) << 4);
      *(u16*)((char*)PsW + byte) = f2b(s[nf][j]);
    }
  }
}

__global__ __launch_bounds__(256) void attn_k(const u16* __restrict__ qkv,
                                              u16* __restrict__ out) {
  __shared__ u16 Ks[2][64 * 128];
  __shared__ u16 Vt[2][128 * 64];
  __shared__ u16 Ps[4][2][16 * 64];
  int t = threadIdx.x, lane = t & 63, w = t >> 6;
  int lrow = lane & 15, lg = lane >> 4;
  int p = blockIdx.x, bh = blockIdx.y;
  int b = bh / 7, h = bh % 7;
  int tA = p, tB = 31 - p;
  int qA = tA * 64 + w * 16, qB = tB * 64 + w * 16;
  const u16* base = qkv + (size_t)b * 2048 * 1152;
  const u16* kb = base + 896;
  const u16* vb = base + 1024;

  bf16x8 qfA[4], qfB[4];
  #pragma unroll
  for (int kk = 0; kk < 4; ++kk) {
    qfA[kk] = *(const bf16x8*)(base + (size_t)(qA + lrow) * 1152 + h * 128 + kk * 32 + lg * 8);
    qfB[kk] = *(const bf16x8*)(base + (size_t)(qB + lrow) * 1152 + h * 128 + kk * 32 + lg * 8);
  }
  f32x4 oaA[8] = {}, oaB[8] = {};
  float mA[4], lA[4], mB[4], lB[4];
  #pragma unroll
  for (int j = 0; j < 4; ++j) { mA[j] = -1e30f; lA[j] = 0.0f; mB[j] = -1e30f; lB[j] = 0.0f; }

  // prologue: stage tile 0
  stageK_sw(Ks[0], kb, 0, t);
  { u16x8 vr[4]; loadV(vr, vb, 0, t); writeVt(Vt[0], vr, t); }
  __syncthreads();

  int cur = 0;
  int ktmax = tB;
  for (int kt = 0; kt <= ktmax; ++kt) {
    bool pre = kt < ktmax;
    u16x8 vr2[4];
    if (pre) { stageK_sw(Ks[cur ^ 1], kb, (kt + 1) * 64, t); loadV(vr2, vb, (kt + 1) * 64, t); }

    bool doA = (kt <= tA);
    int k0 = kt * 64;
    const u16* KsC = Ks[cur];
    const u16* VtC = Vt[cur];

    // QK^T (shared kf loads for both tiles)
    f32x4 saA[4] = {}, saB[4] = {};
    #pragma unroll
    for (int nf = 0; nf < 4; ++nf) {
      bf16x8 kf[4];
      #pragma unroll
      for (int kk = 0; kk < 4; ++kk)
        kf[kk] = ldSw(KsC, nf * 16 + lrow, 256, kk * 64 + lg * 16);
      #pragma unroll
      for (int kk = 0; kk < 4; ++kk)
        saB[nf] = mfma16(qfB[kk], kf[kk], saB[nf]);
      if (doA)
        #pragma unroll
        for (int kk = 0; kk < 4; ++kk)
          saA[nf] = mfma16(qfA[kk], kf[kk], saA[nf]);
    }

    // softmax + P writes
    if (doA) smax_tile(saA, qA, k0, kt == tA, mA, lA, oaA, Ps[w][0], lrow, lg);
    smax_tile(saB, qB, k0, kt == tB, mB, lB, oaB, Ps[w][1], lrow, lg);

    // PV (shared vf loads)
    bf16x8 pfA[2], pfB[2];
    #pragma unroll
    for (int ks = 0; ks < 2; ++ks) {
      pfB[ks] = ldSw(Ps[w][1], lrow, 128, ks * 64 + lg * 16);
      if (doA) pfA[ks] = ldSw(Ps[w][0], lrow, 128, ks * 64 + lg * 16);
    }
    #pragma unroll
    for (int ks = 0; ks < 2; ++ks) {
      bf16x8 vf[8];
      #pragma unroll
      for (int nf2 = 0; nf2 < 8; ++nf2)
        vf[nf2] = ldSw(VtC, nf2 * 16 + lrow, 128, ks * 64 + lg * 16);
      #pragma unroll
      for (int nf2 = 0; nf2 < 8; ++nf2)
        oaB[nf2] = mfma16(pfB[ks], vf[nf2], oaB[nf2]);
      if (doA)
        #pragma unroll
        for (int nf2 = 0; nf2 < 8; ++nf2)
          oaA[nf2] = mfma16(pfA[ks], vf[nf2], oaA[nf2]);
    }

    if (pre) writeVt(Vt[cur ^ 1], vr2, t);
    __syncthreads();
    cur ^= 1;
  }

  // epilogue: normalize + store both tiles
  #pragma unroll
  for (int tile = 0; tile < 2; ++tile) {
    int q0 = tile ? qB : qA;
    const f32x4* oa = tile ? oaB : oaA;
    const float* l = tile ? lB : lA;
    u16* ob = out + ((size_t)b * 2048 + q0) * 896 + h * 128;
    #pragma unroll
    for (int j = 0; j < 4; ++j) {
      float rl = 1.0f / l[j];
      #pragma unroll
      for (int nf2 = 0; nf2 < 8; ++nf2)
        ob[(size_t)(lg * 4 + j) * 896 + nf2 * 16 + lrow] = f2b(oa[nf2][j] * rl);
    }
  }
}

// ---------------------------------------------------------------------------
extern "C" void kernel_launch(void* const* d_in, const int* in_sizes, int n_in,
                              void* d_out, int out_size, void* d_ws, size_t ws_size,
                              hipStream_t stream) {
  const int nX = 4096 * 896, nWQ = 896 * 896, nBQ = 896, nWK = 128 * 896, nBK = 128;
  const int nWV = 128 * 896, nBV = 128, nWO = 896 * 896;
  const int nWG = 4864 * 896, nWU = 4864 * 896, nWD = 896 * 4864;
  const int nLN = 896, nCS = 2048 * 128;

  u16* ws = (u16*)d_ws;
  int* flag = (int*)ws;
  size_t off = 16;
  auto alloc = [&](size_t n) { u16* p = ws + off; off += n; return p; };
  u16* cx   = alloc(nX);
  u16* cwq  = alloc(nWQ);  u16* cbq = alloc(nBQ);
  u16* cwk  = alloc(nWK);  u16* cbk = alloc(nBK);
  u16* cwv  = alloc(nWV);  u16* cbv = alloc(nBV);
  u16* cwo  = alloc(nWO);
  u16* cwg  = alloc(nWG);  u16* cwu = alloc(nWU);  u16* cwd = alloc(nWD);
  u16* cln1 = alloc(nLN);  u16* cln2 = alloc(nLN);
  u16* ccos = alloc(nCS);  u16* csin = alloc(nCS);
  u16* h    = alloc(4096 * 896);
  u16* qkv  = alloc(4096 * 1152);
  u16* attn = alloc(4096 * 896);
  u16* x2   = alloc(4096 * 896);
  u16* act  = alloc((size_t)4096 * 4864);

  detect_k<<<1, 256, 0, stream>>>((const unsigned int*)d_in[0], flag);

  CvtJobs jobs;
  const void* srcs[15] = { d_in[0], d_in[1], d_in[2], d_in[3], d_in[4], d_in[5],
                           d_in[6], d_in[7], d_in[8], d_in[9], d_in[10],
                           d_in[11], d_in[12], d_in[14], d_in[15] };
  u16* dsts[15] = { cx, cwq, cbq, cwk, cbk, cwv, cbv, cwo, cwg, cwu, cwd,
                    cln1, cln2, ccos, csin };
  int  ns[15]   = { nX, nWQ, nBQ, nWK, nBK, nWV, nBV, nWO, nWG, nWU, nWD,
                    nLN, nLN, nCS, nCS };
  for (int i = 0; i < 15; ++i) { jobs.j[i].src = srcs[i]; jobs.j[i].dst = dsts[i]; jobs.j[i].n = ns[i]; }
  convert_k<<<dim3(2128, 15), 256, 0, stream>>>(jobs, flag);

  rmsnorm_k <<<4096, 448, 0, stream>>>(cx, cln1, h);
  gemm_qkv  <<<dim3(9, 32),  256, 0, stream>>>(h, cwq, cbq, cwk, cbk, cwv, cbv, qkv);
  rope_k    <<<dim3(2, 4096), 256, 0, stream>>>(qkv, ccos, csin);
  attn_k    <<<dim3(16, 14), 256, 0, stream>>>(qkv, attn);
  gemm_bt<true, false> <<<dim3(7, 32), 256, 0, stream>>>(attn, cwo, cx, (void*)x2, flag, 896, 896);
  rmsnorm_k <<<4096, 448, 0, stream>>>(x2, cln2, h);
  gemm_gateup <<<dim3(76, 32), 256, 0, stream>>>(h, cwg, cwu, act);
  gemm_bt<true, true> <<<dim3(7, 32), 256, 0, stream>>>(act, cwd, x2, d_out, flag, 4864, 896);
}